// Round 1
// baseline (233.000 us; speedup 1.0000x reference)
//
#include <hip/hip_runtime.h>

// Problem constants (from reference setup_inputs)
#define N_IDS   851968      // 4096*26*8
#define RAW     500000      // raw id universe
#define EMB_DIM 128
#define EPB     1024        // elements per scan block (256 thr * 4 items)
#define NBLK    (N_IDS / EPB)   // 832 (exact)

__device__ __forceinline__ int wave_incl_scan(int v) {
    int lane = threadIdx.x & 63;
#pragma unroll
    for (int d = 1; d < 64; d <<= 1) {
        int n = __shfl_up(v, d, 64);
        if (lane >= d) v += n;
    }
    return v;
}

// Pass 2: first_pos[id] = min position of id
__global__ void k_first_pos(const int* __restrict__ flat, int* __restrict__ first_pos) {
    int i = blockIdx.x * 256 + threadIdx.x;
    if (i < N_IDS) atomicMin(&first_pos[flat[i]], i);
}

// Pass 3: per-block count of first-occurrence flags
__global__ void k_block_sums(const int* __restrict__ flat, const int* __restrict__ first_pos,
                             int* __restrict__ bsums) {
    int tid = threadIdx.x;
    int4 f4 = reinterpret_cast<const int4*>(flat)[blockIdx.x * 256 + tid];
    int base = blockIdx.x * EPB + tid * 4;
    int s = 0;
    s += (first_pos[f4.x] == base + 0);
    s += (first_pos[f4.y] == base + 1);
    s += (first_pos[f4.z] == base + 2);
    s += (first_pos[f4.w] == base + 3);
#pragma unroll
    for (int d = 32; d >= 1; d >>= 1) s += __shfl_down(s, d, 64);
    __shared__ int wsum[4];
    int wid = tid >> 6, lane = tid & 63;
    if (lane == 0) wsum[wid] = s;
    __syncthreads();
    if (tid == 0) bsums[blockIdx.x] = wsum[0] + wsum[1] + wsum[2] + wsum[3];
}

// Pass 4: exclusive scan of NBLK block sums (single block, 1024 threads)
__global__ void k_scan_sums(const int* __restrict__ bsums, int* __restrict__ boff) {
    int tid = threadIdx.x;
    int v = (tid < NBLK) ? bsums[tid] : 0;
    int incl = wave_incl_scan(v);
    __shared__ int wsum[16];
    int wid = tid >> 6, lane = tid & 63;
    if (lane == 63) wsum[wid] = incl;
    __syncthreads();
    int woff = 0;
    for (int w = 0; w < wid; ++w) woff += wsum[w];
    if (tid < NBLK) boff[tid] = woff + incl - v;   // exclusive prefix
}

// Pass 5: recompute flags, full block scan, write slot[id] = first-appearance rank
__global__ void k_rank_slot(const int* __restrict__ flat, const int* __restrict__ first_pos,
                            const int* __restrict__ boff, int* __restrict__ slot) {
    int tid = threadIdx.x;
    int4 f4 = reinterpret_cast<const int4*>(flat)[blockIdx.x * 256 + tid];
    int base = blockIdx.x * EPB + tid * 4;
    int f[4] = {f4.x, f4.y, f4.z, f4.w};
    int flg[4], s = 0;
#pragma unroll
    for (int j = 0; j < 4; ++j) {
        flg[j] = (first_pos[f[j]] == base + j);
        s += flg[j];
    }
    int incl = wave_incl_scan(s);
    __shared__ int wsum[4];
    int wid = tid >> 6, lane = tid & 63;
    if (lane == 63) wsum[wid] = incl;
    __syncthreads();
    int woff = 0;
    for (int w = 0; w < wid; ++w) woff += wsum[w];
    int off = boff[blockIdx.x] + woff + (incl - s);   // global exclusive prefix
#pragma unroll
    for (int j = 0; j < 4; ++j) {
        if (flg[j]) { slot[f[j]] = off; ++off; }
    }
}

// Pass 6: gather rows. One float4 per thread; 32 threads cover one 128-float row.
__global__ void k_gather(const int* __restrict__ flat, const int* __restrict__ slot,
                         const float4* __restrict__ emb, float4* __restrict__ out) {
    int t = blockIdx.x * 256 + threadIdx.x;     // < N_IDS*32 = 27,262,976
    int row = t >> 5;
    int c = t & 31;
    int s = slot[flat[row]];
    out[t] = emb[(size_t)s * 32 + c];
}

extern "C" void kernel_launch(void* const* d_in, const int* in_sizes, int n_in,
                              void* d_out, int out_size, void* d_ws, size_t ws_size,
                              hipStream_t stream) {
    const int*   ids = (const int*)d_in[0];
    const float* emb = (const float*)d_in[1];
    // d_in[2] (default_embedding) is provably never selected: n_unique <= 500000 < 1000000

    char* ws = (char*)d_ws;
    int* first_pos = (int*)(ws);                  // 2,000,000 B
    int* slot      = (int*)(ws + 2000000);        // 2,000,000 B
    int* bsums     = (int*)(ws + 4000000);        // 3,328 B
    int* boff      = (int*)(ws + 4003328);        // 3,328 B

    hipMemsetAsync(first_pos, 0x7F, (size_t)RAW * sizeof(int), stream); // "infinity" > N-1

    k_first_pos <<<(N_IDS + 255) / 256, 256, 0, stream>>>(ids, first_pos);
    k_block_sums<<<NBLK, 256, 0, stream>>>(ids, first_pos, bsums);
    k_scan_sums <<<1, 1024, 0, stream>>>(bsums, boff);
    k_rank_slot <<<NBLK, 256, 0, stream>>>(ids, first_pos, boff, slot);
    k_gather    <<<(N_IDS * 32) / 256, 256, 0, stream>>>(ids, slot,
                     (const float4*)emb, (float4*)d_out);
}

// Round 3
// 194.296 us; speedup vs baseline: 1.1992x; 1.1992x over previous
//
#include <hip/hip_runtime.h>

// Problem constants (from reference setup_inputs)
#define N_IDS   851968      // 4096*26*8
#define RAW     500000      // raw id universe
#define EMB_DIM 128
#define EPB     1024        // elements per scan block (256 thr * 4 items)
#define NBLK    (N_IDS / EPB)   // 832 (exact)
#define TOTAL_F4 (N_IDS * 32)   // 27,262,976 float4 elements in output

typedef float f32x4 __attribute__((ext_vector_type(4)));  // native vec for nontemporal builtins

__device__ __forceinline__ int wave_incl_scan(int v) {
    int lane = threadIdx.x & 63;
#pragma unroll
    for (int d = 1; d < 64; d <<= 1) {
        int n = __shfl_up(v, d, 64);
        if (lane >= d) v += n;
    }
    return v;
}

// Pass 2: first_pos[id] = min position of id
__global__ void k_first_pos(const int* __restrict__ flat, int* __restrict__ first_pos) {
    int i = blockIdx.x * 256 + threadIdx.x;
    if (i < N_IDS) atomicMin(&first_pos[flat[i]], i);
}

// Pass 3: per-block count of first-occurrence flags
__global__ void k_block_sums(const int* __restrict__ flat, const int* __restrict__ first_pos,
                             int* __restrict__ bsums) {
    int tid = threadIdx.x;
    int4 f4 = reinterpret_cast<const int4*>(flat)[blockIdx.x * 256 + tid];
    int base = blockIdx.x * EPB + tid * 4;
    int s = 0;
    s += (first_pos[f4.x] == base + 0);
    s += (first_pos[f4.y] == base + 1);
    s += (first_pos[f4.z] == base + 2);
    s += (first_pos[f4.w] == base + 3);
#pragma unroll
    for (int d = 32; d >= 1; d >>= 1) s += __shfl_down(s, d, 64);
    __shared__ int wsum[4];
    int wid = tid >> 6, lane = tid & 63;
    if (lane == 0) wsum[wid] = s;
    __syncthreads();
    if (tid == 0) bsums[blockIdx.x] = wsum[0] + wsum[1] + wsum[2] + wsum[3];
}

// Pass 4: exclusive scan of NBLK block sums (single block, 1024 threads)
__global__ void k_scan_sums(const int* __restrict__ bsums, int* __restrict__ boff) {
    int tid = threadIdx.x;
    int v = (tid < NBLK) ? bsums[tid] : 0;
    int incl = wave_incl_scan(v);
    __shared__ int wsum[16];
    int wid = tid >> 6, lane = tid & 63;
    if (lane == 63) wsum[wid] = incl;
    __syncthreads();
    int woff = 0;
    for (int w = 0; w < wid; ++w) woff += wsum[w];
    if (tid < NBLK) boff[tid] = woff + incl - v;   // exclusive prefix
}

// Pass 5: recompute flags, full block scan, write slot[id] = first-appearance rank
__global__ void k_rank_slot(const int* __restrict__ flat, const int* __restrict__ first_pos,
                            const int* __restrict__ boff, int* __restrict__ slot) {
    int tid = threadIdx.x;
    int4 f4 = reinterpret_cast<const int4*>(flat)[blockIdx.x * 256 + tid];
    int base = blockIdx.x * EPB + tid * 4;
    int f[4] = {f4.x, f4.y, f4.z, f4.w};
    int flg[4], s = 0;
#pragma unroll
    for (int j = 0; j < 4; ++j) {
        flg[j] = (first_pos[f[j]] == base + j);
        s += flg[j];
    }
    int incl = wave_incl_scan(s);
    __shared__ int wsum[4];
    int wid = tid >> 6, lane = tid & 63;
    if (lane == 63) wsum[wid] = incl;
    __syncthreads();
    int woff = 0;
    for (int w = 0; w < wid; ++w) woff += wsum[w];
    int off = boff[blockIdx.x] + woff + (incl - s);   // global exclusive prefix
#pragma unroll
    for (int j = 0; j < 4; ++j) {
        if (flg[j]) { slot[f[j]] = off; ++off; }
    }
}

// Pass 6: rslot[row] = slot[ids[row]]  (cuts gather's dependent chain to depth 2)
__global__ void k_row_slot(const int* __restrict__ flat, const int* __restrict__ slot,
                           int* __restrict__ rslot) {
    int i = blockIdx.x * 256 + threadIdx.x;   // N_IDS / 256 = 3328 exact
    rslot[i] = slot[flat[i]];
}

// Pass 7: gather. 4 independent float4 chains per thread; nontemporal output
// stores keep the 436 MB write stream out of L2/L3 so the ~209 MB emb
// working set stays L3-resident for its 2.08x re-reads.
__global__ void k_gather(const int* __restrict__ rslot,
                         const f32x4* __restrict__ emb, f32x4* __restrict__ out) {
    const int stride = TOTAL_F4 / 4;                // 6,815,744
    int t = blockIdx.x * 256 + threadIdx.x;         // < stride
    int i0 = t, i1 = t + stride, i2 = t + 2 * stride, i3 = t + 3 * stride;
    int r0 = rslot[i0 >> 5];
    int r1 = rslot[i1 >> 5];
    int r2 = rslot[i2 >> 5];
    int r3 = rslot[i3 >> 5];
    f32x4 v0 = emb[(size_t)r0 * 32 + (i0 & 31)];
    f32x4 v1 = emb[(size_t)r1 * 32 + (i1 & 31)];
    f32x4 v2 = emb[(size_t)r2 * 32 + (i2 & 31)];
    f32x4 v3 = emb[(size_t)r3 * 32 + (i3 & 31)];
    __builtin_nontemporal_store(v0, &out[i0]);
    __builtin_nontemporal_store(v1, &out[i1]);
    __builtin_nontemporal_store(v2, &out[i2]);
    __builtin_nontemporal_store(v3, &out[i3]);
}

extern "C" void kernel_launch(void* const* d_in, const int* in_sizes, int n_in,
                              void* d_out, int out_size, void* d_ws, size_t ws_size,
                              hipStream_t stream) {
    const int*   ids = (const int*)d_in[0];
    const float* emb = (const float*)d_in[1];
    // d_in[2] (default_embedding) is provably never selected: n_unique <= 500000 < 1000000

    char* ws = (char*)d_ws;
    int* first_pos = (int*)(ws);                  // 2,000,000 B
    int* slot      = (int*)(ws + 2000000);        // 2,000,000 B
    int* bsums     = (int*)(ws + 4000000);        // 3,328 B
    int* boff      = (int*)(ws + 4003328);        // 3,328 B
    int* rslot     = (int*)(ws + 4006656);        // 3,407,872 B

    (void)hipMemsetAsync(first_pos, 0x7F, (size_t)RAW * sizeof(int), stream); // "infinity" > N-1

    k_first_pos <<<(N_IDS + 255) / 256, 256, 0, stream>>>(ids, first_pos);
    k_block_sums<<<NBLK, 256, 0, stream>>>(ids, first_pos, bsums);
    k_scan_sums <<<1, 1024, 0, stream>>>(bsums, boff);
    k_rank_slot <<<NBLK, 256, 0, stream>>>(ids, first_pos, boff, slot);
    k_row_slot  <<<N_IDS / 256, 256, 0, stream>>>(ids, slot, rslot);
    k_gather    <<<(TOTAL_F4 / 4) / 256, 256, 0, stream>>>(rslot,
                     (const f32x4*)emb, (f32x4*)d_out);
}